// Round 7
// baseline (132.171 us; speedup 1.0000x reference)
//
#include <hip/hip_runtime.h>

// hex pooling: out[i][c] = max_{k<7} x[hex_idx[i][k]][c]
// MLP probe: each thread handles 32 B (two float4s) of one row -> 14
// independent global_load_dwordx4 in flight per thread. One wave = one full
// 2 KB row per neighbor (contiguous). 256-thread block = 4 rows.
// idx loads wave-uniform -> scalar s_load. Nontemporal out stores.

typedef float v4f __attribute__((ext_vector_type(4)));

__global__ __launch_bounds__(256) void hex_pool_kernel(
        const float* __restrict__ x,
        const int* __restrict__ idx,
        float* __restrict__ out,
        int L, int C4 /* C/4 = 128 */) {
    const int row = blockIdx.x * 4 + (threadIdx.x >> 6);  // wave-uniform
    if (row >= L) return;                                  // uniform guard
    const int col2 = (threadIdx.x & 63) * 2;               // float4 pair index

    const int* __restrict__ ib = idx + (long long)row * 7;
    int r0 = ib[0], r1 = ib[1], r2 = ib[2], r3 = ib[3];
    int r4 = ib[4], r5 = ib[5], r6 = ib[6];

    const v4f* __restrict__ x4 = reinterpret_cast<const v4f*>(x);

    v4f a0 = x4[(long long)r0 * C4 + col2], b0 = x4[(long long)r0 * C4 + col2 + 1];
    v4f a1 = x4[(long long)r1 * C4 + col2], b1 = x4[(long long)r1 * C4 + col2 + 1];
    v4f a2 = x4[(long long)r2 * C4 + col2], b2 = x4[(long long)r2 * C4 + col2 + 1];
    v4f a3 = x4[(long long)r3 * C4 + col2], b3 = x4[(long long)r3 * C4 + col2 + 1];
    v4f a4 = x4[(long long)r4 * C4 + col2], b4 = x4[(long long)r4 * C4 + col2 + 1];
    v4f a5 = x4[(long long)r5 * C4 + col2], b5 = x4[(long long)r5 * C4 + col2 + 1];
    v4f a6 = x4[(long long)r6 * C4 + col2], b6 = x4[(long long)r6 * C4 + col2 + 1];

    v4f ma, mb;
#pragma unroll
    for (int j = 0; j < 4; ++j) {
        ma[j] = fmaxf(fmaxf(fmaxf(a0[j], a1[j]), fmaxf(a2[j], a3[j])),
                      fmaxf(fmaxf(a4[j], a5[j]), a6[j]));
        mb[j] = fmaxf(fmaxf(fmaxf(b0[j], b1[j]), fmaxf(b2[j], b3[j])),
                      fmaxf(fmaxf(b4[j], b5[j]), b6[j]));
    }

    v4f* __restrict__ o = reinterpret_cast<v4f*>(out) + (long long)row * C4 + col2;
    __builtin_nontemporal_store(ma, o);
    __builtin_nontemporal_store(mb, o + 1);
}

extern "C" void kernel_launch(void* const* d_in, const int* in_sizes, int n_in,
                              void* d_out, int out_size, void* d_ws, size_t ws_size,
                              hipStream_t stream) {
    const float* x = (const float*)d_in[0];
    const int* idx = (const int*)d_in[1];
    float* out = (float*)d_out;

    const int K = 7;
    const int n = in_sizes[1] / K;        // 40962
    const int C = in_sizes[0] / n;        // 512
    const int C4 = C / 4;                 // 128
    const int L = out_size / C;           // 10242

    int grid = (L + 3) / 4;               // 4 rows per block
    hex_pool_kernel<<<grid, 256, 0, stream>>>(x, idx, out, L, C4);
}